// Round 1
// baseline (608.761 us; speedup 1.0000x reference)
//
#include <hip/hip_runtime.h>
#include <hip/hip_bf16.h>
#include <cstdint>
#include <cstddef>

// Problem constants
#define NP     100352      // 32*56*56 total pixels
#define HW     3136        // 56*56
#define CDIM   384
#define C3     1152        // 3*384
#define NHEAD  12
#define HD     32          // head dim
#define NWIN   2048        // 32 * 8 * 8 windows

typedef __attribute__((ext_vector_type(8))) short bf16x8;
typedef __attribute__((ext_vector_type(4))) float f32x4;

static __device__ __forceinline__ float bf2f(unsigned short u) {
    union { float f; uint32_t i; } v; v.i = ((uint32_t)u) << 16; return v.f;
}
static __device__ __forceinline__ unsigned short f2bf(float f) {
    union { float f; uint32_t i; } v; v.f = f;
    uint32_t r = v.i + 0x7FFFu + ((v.i >> 16) & 1u);   // round-nearest-even
    return (unsigned short)(r >> 16);
}
// pack two f32 -> bf16 pair (round-half-up; lo half = a)
static __device__ __forceinline__ uint32_t pk2(float a, float b) {
    union { float f; uint32_t u; } x, y; x.f = a; y.f = b;
    return ((x.u + 0x8000u) >> 16) | ((y.u + 0x8000u) & 0xffff0000u);
}

// async global->LDS, 16B per lane; LDS dest = uniform base + lane*16
static __device__ __forceinline__ void gld_lds16(const void* g, void* l) {
    __builtin_amdgcn_global_load_lds(
        (const __attribute__((address_space(1))) void*)g,
        (__attribute__((address_space(3))) void*)l, 16, 0, 0);
}

// ---------------------------------------------------------------------------
// Kernel 1: fp32 -> bf16 weight conversion (vectorized x4)
// ---------------------------------------------------------------------------
__global__ __launch_bounds__(256) void cvt_f32_bf16(
    const float* __restrict__ src, unsigned short* __restrict__ dst, int n4) {
    int i = blockIdx.x * blockDim.x + threadIdx.x;
    if (i < n4) {
        float4 v = ((const float4*)src)[i];
        ushort4 r;
        r.x = f2bf(v.x); r.y = f2bf(v.y); r.z = f2bf(v.z); r.w = f2bf(v.w);
        ((ushort4*)dst)[i] = r;
    }
}

// ---------------------------------------------------------------------------
// Kernel 1b: precompute bias_t[h][query][key] fp32 (64x64 padded, / scale,
// -1e30 on pads so softmax masking is free). 12*64*64 = 49152 elems.
// ---------------------------------------------------------------------------
__global__ __launch_bounds__(256) void bias_pre(
    const float* __restrict__ btab, float* __restrict__ bias_t) {
    int idx = blockIdx.x * 256 + threadIdx.x;
    int h = idx >> 12, query = (idx >> 6) & 63, key = idx & 63;
    float v = -1e30f;
    if (query < 49 && key < 49) {
        int ri = query / 7, rj = query % 7, mi = key / 7, mj = key % 7;
        v = btab[((ri - mi + 6) * 13 + (rj - mj + 6)) * NHEAD + h] * 5.656854249492381f;
    }
    bias_t[idx] = v;
}

// ---------------------------------------------------------------------------
// Kernel 2: transpose x (B, C, HW) fp32 -> xt (B*HW, C) bf16
// grid (98, 12, 32), block (32, 8)
// ---------------------------------------------------------------------------
__global__ __launch_bounds__(256) void transpose_x(
    const float* __restrict__ x, unsigned short* __restrict__ xt) {
    __shared__ float tile[32][33];
    int b   = blockIdx.z;
    int hw0 = blockIdx.x * 32;
    int c0  = blockIdx.y * 32;
    int tx = threadIdx.x, ty = threadIdx.y;
    const float* xp = x + (size_t)b * CDIM * HW;
#pragma unroll
    for (int i = 0; i < 4; i++) {
        int c = ty + i * 8;
        tile[c][tx] = xp[(size_t)(c0 + c) * HW + hw0 + tx];   // coalesced along hw
    }
    __syncthreads();
    unsigned short* xtp = xt + (size_t)b * HW * CDIM;
#pragma unroll
    for (int i = 0; i < 4; i++) {
        int r = ty + i * 8;                                   // local hw
        xtp[(size_t)(hw0 + r) * CDIM + c0 + tx] = f2bf(tile[tx][r]);  // coalesced along c
    }
}

// ---------------------------------------------------------------------------
// MFMA GEMM main loop (m97 structure). K = 384 fixed.
// ---------------------------------------------------------------------------
static __device__ __forceinline__ void gemm_main(
    const unsigned short* __restrict__ A, const unsigned short* __restrict__ Bt,
    int m0, int n0, unsigned short* As, unsigned short* Bs, f32x4 acc[4][4]) {

    int tid  = threadIdx.x;
    int wv   = tid >> 6;
    int lane = tid & 63;
    int wr = wv >> 1, wc = wv & 1;
    int lrow = lane & 15, lq = lane >> 4;

#pragma unroll
    for (int mi = 0; mi < 4; mi++)
#pragma unroll
        for (int ni = 0; ni < 4; ni++)
            acc[mi][ni] = (f32x4){0.f, 0.f, 0.f, 0.f};

    for (int kt = 0; kt < 12; kt++) {   // K = 384 = 12 * 32
#pragma unroll
        for (int i = 0; i < 2; i++) {
            int ch  = wv * 2 + i;
            int row = ch * 16 + (lane >> 2);
            int seg = lane & 3;
            gld_lds16(A  + (size_t)(m0 + row) * 384 + kt * 32 + seg * 8, As + ch * 512);
            gld_lds16(Bt + (size_t)(n0 + row) * 384 + kt * 32 + seg * 8, Bs + ch * 512);
        }
        __syncthreads();

        bf16x8 af[4], bfr[4];
#pragma unroll
        for (int mi = 0; mi < 4; mi++)
            af[mi] = *(const bf16x8*)(As + (wr * 64 + mi * 16 + lrow) * 32 + lq * 8);
#pragma unroll
        for (int ni = 0; ni < 4; ni++)
            bfr[ni] = *(const bf16x8*)(Bs + (wc * 64 + ni * 16 + lrow) * 32 + lq * 8);
#pragma unroll
        for (int mi = 0; mi < 4; mi++)
#pragma unroll
            for (int ni = 0; ni < 4; ni++)
                acc[mi][ni] = __builtin_amdgcn_mfma_f32_16x16x32_bf16(
                    af[mi], bfr[ni], acc[mi][ni], 0, 0, 0);
        __syncthreads();
    }
}

// GEMM 1: qkv_t[p][o] = sum_c xt[p][c] * w_qkv[o][c]; output bf16, ldc = 1152
// XCD-chunked swizzle: 7056 blocks = 8 XCDs * 882. Each XCD owns a
// contiguous m-major chunk (98 m-panels x 9 n-tiles) so the 9 blocks
// sharing one 98 KB A-panel hit the SAME per-XCD L2 (panels fetched ~once).
__global__ __launch_bounds__(256) void gemm_qkv(
    const unsigned short* __restrict__ A, const unsigned short* __restrict__ Bt,
    unsigned short* __restrict__ C) {
    __shared__ __align__(16) unsigned short As[128 * 32];
    __shared__ __align__(16) unsigned short Bs[128 * 32];
    int lin = blockIdx.y * 9 + blockIdx.x;     // hardware dispatch order
    int xcd = lin & 7;                         // round-robin XCD assignment
    int pos = lin >> 3;
    int nid = xcd * 882 + pos;                 // bijective: 7056 = 8*882
    int m0 = (nid / 9) * 128;
    int n0 = (nid % 9) * 128;
    f32x4 acc[4][4];
    gemm_main(A, Bt, m0, n0, As, Bs, acc);

    int lane = threadIdx.x & 63, wv = threadIdx.x >> 6;
    int wr = wv >> 1, wc = wv & 1;
    int lrow = lane & 15, lq = lane >> 4;
#pragma unroll
    for (int mi = 0; mi < 4; mi++)
#pragma unroll
        for (int ni = 0; ni < 4; ni++)
#pragma unroll
            for (int i = 0; i < 4; i++) {
                int row = m0 + wr * 64 + mi * 16 + lq * 4 + i;   // p
                int col = n0 + wc * 64 + ni * 16 + lrow;         // o
                C[(size_t)row * C3 + col] = f2bf(acc[mi][ni][i]);
            }
}

// GEMM 2: out[b][o][hw] = sum_c w_proj[o][c] * out_t[p][c] + b_proj[o]
// XCD-chunked swizzle: 2352 blocks = 8 * 294. n-major within chunk so the
// 3 m-blocks sharing one outt panel are adjacent on the same XCD L2.
__global__ __launch_bounds__(256) void gemm_proj(
    const unsigned short* __restrict__ A, const unsigned short* __restrict__ Bt,
    const float* __restrict__ bias, float* __restrict__ out) {
    __shared__ __align__(16) unsigned short As[128 * 32];
    __shared__ __align__(16) unsigned short Bs[128 * 32];
    int lin = blockIdx.y * 784 + blockIdx.x;   // hardware dispatch order
    int xcd = lin & 7;
    int pos = lin >> 3;
    int nid = xcd * 294 + pos;                 // bijective: 2352 = 8*294
    int m0 = (nid % 3) * 128;
    int n0 = (nid / 3) * 128;
    f32x4 acc[4][4];
    gemm_main(A, Bt, m0, n0, As, Bs, acc);

    int lane = threadIdx.x & 63, wv = threadIdx.x >> 6;
    int wr = wv >> 1, wc = wv & 1;
    int lrow = lane & 15, lq = lane >> 4;
#pragma unroll
    for (int mi = 0; mi < 4; mi++)
#pragma unroll
        for (int ni = 0; ni < 4; ni++) {
            int pcol = n0 + wc * 64 + ni * 16 + lrow;            // global pixel p
            int b = pcol / HW, hw = pcol - b * HW;
#pragma unroll
            for (int i = 0; i < 4; i++) {
                int o = m0 + wr * 64 + mi * 16 + lq * 4 + i;
                out[(size_t)b * CDIM * HW + (size_t)o * HW + hw] = acc[mi][ni][i] + bias[o];
            }
        }
}

// ---------------------------------------------------------------------------
// Kernel 4: MFMA window attention. grid (2048, 12), block 64 (1 wave).
// Computes S^T = K.Q^T (A=K, B=Q frags read DIRECTLY from qkvt: natural
// layout), C-init = bias_t[h][query][key] (bias/scale, -1e30 pads -> free
// masking). Softmax over keys = per-lane 16-reg reduce + shfl_xor(16,32).
// P[query][key] -> LDS (rows padded to 72 elems, 16B-aligned b128 reads).
// O^T = V^T.P^T via MFMA; V^T built by b16 scatter at staging.
// ---------------------------------------------------------------------------
__global__ __launch_bounds__(64, 3) void attn_mfma(
    const unsigned short* __restrict__ qkv, const float* __restrict__ bias_t,
    unsigned short* __restrict__ outt) {
    int w = blockIdx.x, h = blockIdx.y;
    int lane = threadIdx.x;
    int q = lane >> 4, c15 = lane & 15;
    int b = w >> 6, wy = (w >> 3) & 7, wx = w & 7;
    int pbase = b * HW + wy * 7 * 56 + wx * 7;

    __shared__ __align__(16) unsigned short sVT[32 * 72];  // V^T[d][key]
    __shared__ __align__(16) unsigned short sP[64 * 72];   // P[query][key]

    // token -> pixel for tile index t (used by Q/K frags and O stores)
    int p_t[4]; int valid[4];
#pragma unroll
    for (int t = 0; t < 4; t++) {
        int tok = c15 + 16 * t;
        valid[t] = tok < 49;
        int tc = valid[t] ? tok : 48;             // clamp (finite garbage; bias masks)
        p_t[t] = pbase + (tc / 7) * 56 + (tc % 7);
    }

    // zero V^T (pad key columns must be finite)
    {
        uint4* z = (uint4*)sVT;                   // 32*72*2/16 = 288 chunks
#pragma unroll
        for (int i = 0; i < 5; i++) {
            int idx = lane + 64 * i;
            if (idx < 288) z[idx] = (uint4){0u, 0u, 0u, 0u};
        }
    }

    // K,Q fragments straight from global: frag[row=lane&15][k=q*8+j]
    bf16x8 kf[4], qf[4];
#pragma unroll
    for (int t = 0; t < 4; t++) {
        const unsigned short* base = qkv + (size_t)p_t[t] * C3 + h * HD + q * 8;
        qf[t] = *(const bf16x8*)(base);           // Q at o-offset 0
        kf[t] = *(const bf16x8*)(base + CDIM);    // K at o-offset 384
    }

    // stage V transposed: sVT[d][tok]
#pragma unroll
    for (int it = 0; it < 4; it++) {
        int c = lane + 64 * it;
        if (c < 196) {
            int tok = c >> 2, s = c & 3;
            int p = pbase + (tok / 7) * 56 + (tok % 7);
            uint4 v = *(const uint4*)(qkv + (size_t)p * C3 + 2 * CDIM + h * HD + s * 8);
            const unsigned short* vp = (const unsigned short*)&v;
#pragma unroll
            for (int i = 0; i < 8; i++)
                sVT[(8 * s + i) * 72 + tok] = vp[i];
        }
    }

    // S^T accumulators, C-init with bias_t[h][query][key] (float4-aligned)
    f32x4 acc[4][4];
    const float* bp = bias_t + (size_t)h * 64 * 64;
#pragma unroll
    for (int nt = 0; nt < 4; nt++) {
        const float* bq = bp + (c15 + 16 * nt) * 64 + 4 * q;
#pragma unroll
        for (int mt = 0; mt < 4; mt++)
            acc[mt][nt] = *(const f32x4*)(bq + 16 * mt);
    }

    // QK^T (K=32 in one MFMA step): acc[key-tile][query-tile]
#pragma unroll
    for (int mt = 0; mt < 4; mt++)
#pragma unroll
        for (int nt = 0; nt < 4; nt++)
            acc[mt][nt] = __builtin_amdgcn_mfma_f32_16x16x32_bf16(
                kf[mt], qf[nt], acc[mt][nt], 0, 0, 0);

    // softmax over keys, per query column; scale folded into exp2 constant:
    // S_ref = scale*(QK + bias/scale)  =>  e = exp2((acc - max) * scale*log2e)
    const float KSC = 0.25503472f;                // 2^-2.5 * log2(e)
#pragma unroll
    for (int nt = 0; nt < 4; nt++) {
        float mx = acc[0][nt][0];
#pragma unroll
        for (int mt = 0; mt < 4; mt++)
#pragma unroll
            for (int r = 0; r < 4; r++) mx = fmaxf(mx, acc[mt][nt][r]);
        mx = fmaxf(mx, __shfl_xor(mx, 16));
        mx = fmaxf(mx, __shfl_xor(mx, 32));
        float sum = 0.f;
#pragma unroll
        for (int mt = 0; mt < 4; mt++)
#pragma unroll
            for (int r = 0; r < 4; r++) {
                float e = exp2f((acc[mt][nt][r] - mx) * KSC);
                acc[mt][nt][r] = e;
                sum += e;
            }
        sum += __shfl_xor(sum, 16);
        sum += __shfl_xor(sum, 32);
        float inv = 1.0f / sum;
        // pack 4 consecutive keys -> ds_write_b64 into P[query][key]
#pragma unroll
        for (int mt = 0; mt < 4; mt++) {
            uint32_t u01 = pk2(acc[mt][nt][0] * inv, acc[mt][nt][1] * inv);
            uint32_t u23 = pk2(acc[mt][nt][2] * inv, acc[mt][nt][3] * inv);
            *(uint2*)(sP + (c15 + 16 * nt) * 72 + 4 * q + 16 * mt) =
                make_uint2(u01, u23);
        }
    }

    // PV: O^T[d][query] = sum_key V^T[d][key] * P[query][key]
    bf16x8 pf[4][2], vf[2][2];
#pragma unroll
    for (int nt = 0; nt < 4; nt++)
#pragma unroll
        for (int ks = 0; ks < 2; ks++)
            pf[nt][ks] = *(const bf16x8*)(sP + (c15 + 16 * nt) * 72 + q * 8 + 32 * ks);
#pragma unroll
    for (int mt = 0; mt < 2; mt++)
#pragma unroll
        for (int ks = 0; ks < 2; ks++)
            vf[mt][ks] = *(const bf16x8*)(sVT + (c15 + 16 * mt) * 72 + q * 8 + 32 * ks);

    f32x4 oacc[2][4];
#pragma unroll
    for (int mt = 0; mt < 2; mt++)
#pragma unroll
        for (int nt = 0; nt < 4; nt++)
            oacc[mt][nt] = (f32x4){0.f, 0.f, 0.f, 0.f};
#pragma unroll
    for (int ks = 0; ks < 2; ks++)
#pragma unroll
        for (int mt = 0; mt < 2; mt++)
#pragma unroll
            for (int nt = 0; nt < 4; nt++)
                oacc[mt][nt] = __builtin_amdgcn_mfma_f32_16x16x32_bf16(
                    vf[mt][ks], pf[nt][ks], oacc[mt][nt], 0, 0, 0);

    // store: lane's query col = c15+16nt (valid<49), rows d = 4q+r+16mt
#pragma unroll
    for (int nt = 0; nt < 4; nt++) {
        if (valid[nt]) {
            unsigned short* dst = outt + (size_t)p_t[nt] * CDIM + h * HD + 4 * q;
#pragma unroll
            for (int mt = 0; mt < 2; mt++) {
                uint32_t u01 = pk2(oacc[mt][nt][0], oacc[mt][nt][1]);
                uint32_t u23 = pk2(oacc[mt][nt][2], oacc[mt][nt][3]);
                *(uint2*)(dst + 16 * mt) = make_uint2(u01, u23);
            }
        }
    }
}

// ---------------------------------------------------------------------------
// Launch
// ---------------------------------------------------------------------------
extern "C" void kernel_launch(void* const* d_in, const int* in_sizes, int n_in,
                              void* d_out, int out_size, void* d_ws, size_t ws_size,
                              hipStream_t stream) {
    const float* x      = (const float*)d_in[0];
    const float* w_qkv  = (const float*)d_in[1];
    const float* btab   = (const float*)d_in[2];
    const float* w_proj = (const float*)d_in[3];
    const float* b_proj = (const float*)d_in[4];
    float* out = (float*)d_out;

    // workspace layout (bytes)
    char* ws = (char*)d_ws;
    const size_t off_xt   = 0;                         // 77,070,336 (reused as out_t)
    const size_t off_qkv  = 77070336;                  // 231,211,008
    const size_t off_wq   = off_qkv + 231211008;       // 884,736
    const size_t off_wp   = off_wq + 884736;           // 294,912
    const size_t off_bt   = off_wp + 294912;           // 196,608
    unsigned short* xt   = (unsigned short*)(ws + off_xt);
    unsigned short* qkvt = (unsigned short*)(ws + off_qkv);
    unsigned short* wqb  = (unsigned short*)(ws + off_wq);
    unsigned short* wpb  = (unsigned short*)(ws + off_wp);
    float*          bt   = (float*)(ws + off_bt);
    unsigned short* outt = xt;   // alias: xt dead after gemm_qkv

    cvt_f32_bf16<<<(C3 * CDIM / 4 + 255) / 256, 256, 0, stream>>>(w_qkv, wqb, C3 * CDIM / 4);
    cvt_f32_bf16<<<(CDIM * CDIM / 4 + 255) / 256, 256, 0, stream>>>(w_proj, wpb, CDIM * CDIM / 4);
    bias_pre<<<192, 256, 0, stream>>>(btab, bt);
    transpose_x<<<dim3(98, 12, 32), dim3(32, 8), 0, stream>>>(x, xt);
    gemm_qkv<<<dim3(9, 784), 256, 0, stream>>>(xt, wqb, qkvt);
    attn_mfma<<<dim3(NWIN, NHEAD), 64, 0, stream>>>(qkvt, bt, outt);
    gemm_proj<<<dim3(784, 3), 256, 0, stream>>>(wpb, outt, b_proj, out);
}

// Round 2
// 600.867 us; speedup vs baseline: 1.0131x; 1.0131x over previous
//
#include <hip/hip_runtime.h>
#include <hip/hip_bf16.h>
#include <cstdint>
#include <cstddef>

// Problem constants
#define NP     100352      // 32*56*56 total pixels
#define HW     3136        // 56*56
#define CDIM   384
#define C3     1152        // 3*384
#define NHEAD  12
#define HD     32          // head dim
#define NWIN   2048        // 32 * 8 * 8 windows

typedef __attribute__((ext_vector_type(8))) short bf16x8;
typedef __attribute__((ext_vector_type(4))) float f32x4;

static __device__ __forceinline__ float bf2f(unsigned short u) {
    union { float f; uint32_t i; } v; v.i = ((uint32_t)u) << 16; return v.f;
}
static __device__ __forceinline__ unsigned short f2bf(float f) {
    union { float f; uint32_t i; } v; v.f = f;
    uint32_t r = v.i + 0x7FFFu + ((v.i >> 16) & 1u);   // round-nearest-even
    return (unsigned short)(r >> 16);
}
// pack two f32 -> bf16 pair (round-half-up; lo half = a)
static __device__ __forceinline__ uint32_t pk2(float a, float b) {
    union { float f; uint32_t u; } x, y; x.f = a; y.f = b;
    return ((x.u + 0x8000u) >> 16) | ((y.u + 0x8000u) & 0xffff0000u);
}

// async global->LDS, 16B per lane; LDS dest = uniform base + lane*16
static __device__ __forceinline__ void gld_lds16(const void* g, void* l) {
    __builtin_amdgcn_global_load_lds(
        (const __attribute__((address_space(1))) void*)g,
        (__attribute__((address_space(3))) void*)l, 16, 0, 0);
}

// ---------------------------------------------------------------------------
// Kernel 1: fp32 -> bf16 weight conversion (vectorized x4)
// ---------------------------------------------------------------------------
__global__ __launch_bounds__(256) void cvt_f32_bf16(
    const float* __restrict__ src, unsigned short* __restrict__ dst, int n4) {
    int i = blockIdx.x * blockDim.x + threadIdx.x;
    if (i < n4) {
        float4 v = ((const float4*)src)[i];
        ushort4 r;
        r.x = f2bf(v.x); r.y = f2bf(v.y); r.z = f2bf(v.z); r.w = f2bf(v.w);
        ((ushort4*)dst)[i] = r;
    }
}

// ---------------------------------------------------------------------------
// Kernel 1b: precompute bias_t[h][query][key] fp32 (64x64 padded, / scale,
// -1e30 on pads so softmax masking is free). 12*64*64 = 49152 elems.
// ---------------------------------------------------------------------------
__global__ __launch_bounds__(256) void bias_pre(
    const float* __restrict__ btab, float* __restrict__ bias_t) {
    int idx = blockIdx.x * 256 + threadIdx.x;
    int h = idx >> 12, query = (idx >> 6) & 63, key = idx & 63;
    float v = -1e30f;
    if (query < 49 && key < 49) {
        int ri = query / 7, rj = query % 7, mi = key / 7, mj = key % 7;
        v = btab[((ri - mi + 6) * 13 + (rj - mj + 6)) * NHEAD + h] * 5.656854249492381f;
    }
    bias_t[idx] = v;
}

// ---------------------------------------------------------------------------
// Kernel 2: transpose x (B, C, HW) fp32 -> xt (B*HW, C) bf16
// grid (98, 12, 32), block (32, 8)
// ---------------------------------------------------------------------------
__global__ __launch_bounds__(256) void transpose_x(
    const float* __restrict__ x, unsigned short* __restrict__ xt) {
    __shared__ float tile[32][33];
    int b   = blockIdx.z;
    int hw0 = blockIdx.x * 32;
    int c0  = blockIdx.y * 32;
    int tx = threadIdx.x, ty = threadIdx.y;
    const float* xp = x + (size_t)b * CDIM * HW;
#pragma unroll
    for (int i = 0; i < 4; i++) {
        int c = ty + i * 8;
        tile[c][tx] = xp[(size_t)(c0 + c) * HW + hw0 + tx];   // coalesced along hw
    }
    __syncthreads();
    unsigned short* xtp = xt + (size_t)b * HW * CDIM;
#pragma unroll
    for (int i = 0; i < 4; i++) {
        int r = ty + i * 8;                                   // local hw
        xtp[(size_t)(hw0 + r) * CDIM + c0 + tx] = f2bf(tile[tx][r]);  // coalesced along c
    }
}

// ---------------------------------------------------------------------------
// MFMA GEMM main loop, 2-phase double-buffered (T3-minimum). K = 384 fixed.
// Per K-step: issue next tile's global_load_lds into alt buffer FIRST, then
// ds_read+MFMA current buffer, then ONE __syncthreads (vmcnt drain lands
// after ~930cy of MFMA has covered the load latency).
// ---------------------------------------------------------------------------
static __device__ __forceinline__ void stage_tile(
    const unsigned short* __restrict__ A, const unsigned short* __restrict__ Bt,
    int m0, int n0, int kt, unsigned short* As, unsigned short* Bs,
    int wv, int lane) {
#pragma unroll
    for (int i = 0; i < 2; i++) {
        int ch  = wv * 2 + i;
        int row = ch * 16 + (lane >> 2);
        int seg = lane & 3;
        gld_lds16(A  + (size_t)(m0 + row) * 384 + kt * 32 + seg * 8, As + ch * 512);
        gld_lds16(Bt + (size_t)(n0 + row) * 384 + kt * 32 + seg * 8, Bs + ch * 512);
    }
}

static __device__ __forceinline__ void gemm_main(
    const unsigned short* __restrict__ A, const unsigned short* __restrict__ Bt,
    int m0, int n0, unsigned short* As, unsigned short* Bs, f32x4 acc[4][4]) {

    int tid  = threadIdx.x;
    int wv   = tid >> 6;
    int lane = tid & 63;
    int wr = wv >> 1, wc = wv & 1;
    int lrow = lane & 15, lq = lane >> 4;

#pragma unroll
    for (int mi = 0; mi < 4; mi++)
#pragma unroll
        for (int ni = 0; ni < 4; ni++)
            acc[mi][ni] = (f32x4){0.f, 0.f, 0.f, 0.f};

    // prologue: stage tile 0 into buffer 0
    stage_tile(A, Bt, m0, n0, 0, As, Bs, wv, lane);
    __syncthreads();

    for (int kt = 0; kt < 12; kt++) {   // K = 384 = 12 * 32
        int cur = kt & 1;
        // issue next-tile loads into the alternate buffer (before compute)
        if (kt < 11)
            stage_tile(A, Bt, m0, n0, kt + 1,
                       As + (cur ^ 1) * 4096, Bs + (cur ^ 1) * 4096, wv, lane);

        const unsigned short* as = As + cur * 4096;
        const unsigned short* bs = Bs + cur * 4096;
        bf16x8 af[4], bfr[4];
#pragma unroll
        for (int mi = 0; mi < 4; mi++)
            af[mi] = *(const bf16x8*)(as + (wr * 64 + mi * 16 + lrow) * 32 + lq * 8);
#pragma unroll
        for (int ni = 0; ni < 4; ni++)
            bfr[ni] = *(const bf16x8*)(bs + (wc * 64 + ni * 16 + lrow) * 32 + lq * 8);
#pragma unroll
        for (int mi = 0; mi < 4; mi++)
#pragma unroll
            for (int ni = 0; ni < 4; ni++)
                acc[mi][ni] = __builtin_amdgcn_mfma_f32_16x16x32_bf16(
                    af[mi], bfr[ni], acc[mi][ni], 0, 0, 0);
        // one barrier per K-step: waits next-tile loads (vmcnt) + all waves
        // done reading 'cur' before it is overwritten in kt+2
        __syncthreads();
    }
}

// GEMM 1: qkv_t[p][o] = sum_c xt[p][c] * w_qkv[o][c]; output bf16, ldc = 1152
// XCD-chunked swizzle: 7056 blocks = 8 XCDs * 882. Each XCD owns a
// contiguous m-major chunk (98 m-panels x 9 n-tiles) so the 9 blocks
// sharing one 98 KB A-panel hit the SAME per-XCD L2 (panels fetched ~once).
__global__ __launch_bounds__(256) void gemm_qkv(
    const unsigned short* __restrict__ A, const unsigned short* __restrict__ Bt,
    unsigned short* __restrict__ C) {
    __shared__ __align__(16) unsigned short As[2 * 128 * 32];
    __shared__ __align__(16) unsigned short Bs[2 * 128 * 32];
    int lin = blockIdx.y * 9 + blockIdx.x;     // hardware dispatch order
    int xcd = lin & 7;                         // round-robin XCD assignment
    int pos = lin >> 3;
    int nid = xcd * 882 + pos;                 // bijective: 7056 = 8*882
    int m0 = (nid / 9) * 128;
    int n0 = (nid % 9) * 128;
    f32x4 acc[4][4];
    gemm_main(A, Bt, m0, n0, As, Bs, acc);

    int lane = threadIdx.x & 63, wv = threadIdx.x >> 6;
    int wr = wv >> 1, wc = wv & 1;
    int lrow = lane & 15, lq = lane >> 4;
#pragma unroll
    for (int mi = 0; mi < 4; mi++)
#pragma unroll
        for (int ni = 0; ni < 4; ni++)
#pragma unroll
            for (int i = 0; i < 4; i++) {
                int row = m0 + wr * 64 + mi * 16 + lq * 4 + i;   // p
                int col = n0 + wc * 64 + ni * 16 + lrow;         // o
                C[(size_t)row * C3 + col] = f2bf(acc[mi][ni][i]);
            }
}

// GEMM 2: out[b][o][hw] = sum_c w_proj[o][c] * out_t[p][c] + b_proj[o]
// XCD-chunked swizzle: 2352 blocks = 8 * 294. n-major within chunk so the
// 3 m-blocks sharing one outt panel are adjacent on the same XCD L2.
__global__ __launch_bounds__(256) void gemm_proj(
    const unsigned short* __restrict__ A, const unsigned short* __restrict__ Bt,
    const float* __restrict__ bias, float* __restrict__ out) {
    __shared__ __align__(16) unsigned short As[2 * 128 * 32];
    __shared__ __align__(16) unsigned short Bs[2 * 128 * 32];
    int lin = blockIdx.y * 784 + blockIdx.x;   // hardware dispatch order
    int xcd = lin & 7;
    int pos = lin >> 3;
    int nid = xcd * 294 + pos;                 // bijective: 2352 = 8*294
    int m0 = (nid % 3) * 128;
    int n0 = (nid / 3) * 128;
    f32x4 acc[4][4];
    gemm_main(A, Bt, m0, n0, As, Bs, acc);

    int lane = threadIdx.x & 63, wv = threadIdx.x >> 6;
    int wr = wv >> 1, wc = wv & 1;
    int lrow = lane & 15, lq = lane >> 4;
#pragma unroll
    for (int mi = 0; mi < 4; mi++)
#pragma unroll
        for (int ni = 0; ni < 4; ni++) {
            int pcol = n0 + wc * 64 + ni * 16 + lrow;            // global pixel p
            int b = pcol / HW, hw = pcol - b * HW;
#pragma unroll
            for (int i = 0; i < 4; i++) {
                int o = m0 + wr * 64 + mi * 16 + lq * 4 + i;
                out[(size_t)b * CDIM * HW + (size_t)o * HW + hw] = acc[mi][ni][i] + bias[o];
            }
        }
}

// ---------------------------------------------------------------------------
// Kernel 4: MFMA window attention. grid (2048, 12), block 64 (1 wave).
// Computes S^T = K.Q^T (A=K, B=Q frags read DIRECTLY from qkvt: natural
// layout), C-init = bias_t[h][query][key] (bias/scale, -1e30 pads -> free
// masking). Softmax over keys = per-lane 16-reg reduce + shfl_xor(16,32).
// P[query][key] -> LDS (rows padded to 72 elems, 16B-aligned b128 reads).
// O^T = V^T.P^T via MFMA; V^T built by b16 scatter at staging.
// ---------------------------------------------------------------------------
__global__ __launch_bounds__(64, 3) void attn_mfma(
    const unsigned short* __restrict__ qkv, const float* __restrict__ bias_t,
    unsigned short* __restrict__ outt) {
    int w = blockIdx.x, h = blockIdx.y;
    int lane = threadIdx.x;
    int q = lane >> 4, c15 = lane & 15;
    int b = w >> 6, wy = (w >> 3) & 7, wx = w & 7;
    int pbase = b * HW + wy * 7 * 56 + wx * 7;

    __shared__ __align__(16) unsigned short sVT[32 * 72];  // V^T[d][key]
    __shared__ __align__(16) unsigned short sP[64 * 72];   // P[query][key]

    // token -> pixel for tile index t (used by Q/K frags and O stores)
    int p_t[4]; int valid[4];
#pragma unroll
    for (int t = 0; t < 4; t++) {
        int tok = c15 + 16 * t;
        valid[t] = tok < 49;
        int tc = valid[t] ? tok : 48;             // clamp (finite garbage; bias masks)
        p_t[t] = pbase + (tc / 7) * 56 + (tc % 7);
    }

    // zero V^T (pad key columns must be finite)
    {
        uint4* z = (uint4*)sVT;                   // 32*72*2/16 = 288 chunks
#pragma unroll
        for (int i = 0; i < 5; i++) {
            int idx = lane + 64 * i;
            if (idx < 288) z[idx] = (uint4){0u, 0u, 0u, 0u};
        }
    }

    // K,Q fragments straight from global: frag[row=lane&15][k=q*8+j]
    bf16x8 kf[4], qf[4];
#pragma unroll
    for (int t = 0; t < 4; t++) {
        const unsigned short* base = qkv + (size_t)p_t[t] * C3 + h * HD + q * 8;
        qf[t] = *(const bf16x8*)(base);           // Q at o-offset 0
        kf[t] = *(const bf16x8*)(base + CDIM);    // K at o-offset 384
    }

    // stage V transposed: sVT[d][tok]
#pragma unroll
    for (int it = 0; it < 4; it++) {
        int c = lane + 64 * it;
        if (c < 196) {
            int tok = c >> 2, s = c & 3;
            int p = pbase + (tok / 7) * 56 + (tok % 7);
            uint4 v = *(const uint4*)(qkv + (size_t)p * C3 + 2 * CDIM + h * HD + s * 8);
            const unsigned short* vp = (const unsigned short*)&v;
#pragma unroll
            for (int i = 0; i < 8; i++)
                sVT[(8 * s + i) * 72 + tok] = vp[i];
        }
    }

    // S^T accumulators, C-init with bias_t[h][query][key] (float4-aligned)
    f32x4 acc[4][4];
    const float* bp = bias_t + (size_t)h * 64 * 64;
#pragma unroll
    for (int nt = 0; nt < 4; nt++) {
        const float* bq = bp + (c15 + 16 * nt) * 64 + 4 * q;
#pragma unroll
        for (int mt = 0; mt < 4; mt++)
            acc[mt][nt] = *(const f32x4*)(bq + 16 * mt);
    }

    // QK^T (K=32 in one MFMA step): acc[key-tile][query-tile]
#pragma unroll
    for (int mt = 0; mt < 4; mt++)
#pragma unroll
        for (int nt = 0; nt < 4; nt++)
            acc[mt][nt] = __builtin_amdgcn_mfma_f32_16x16x32_bf16(
                kf[mt], qf[nt], acc[mt][nt], 0, 0, 0);

    // softmax over keys, per query column; scale folded into exp2 constant:
    // S_ref = scale*(QK + bias/scale)  =>  e = exp2((acc - max) * scale*log2e)
    const float KSC = 0.25503472f;                // 2^-2.5 * log2(e)
#pragma unroll
    for (int nt = 0; nt < 4; nt++) {
        float mx = acc[0][nt][0];
#pragma unroll
        for (int mt = 0; mt < 4; mt++)
#pragma unroll
            for (int r = 0; r < 4; r++) mx = fmaxf(mx, acc[mt][nt][r]);
        mx = fmaxf(mx, __shfl_xor(mx, 16));
        mx = fmaxf(mx, __shfl_xor(mx, 32));
        float sum = 0.f;
#pragma unroll
        for (int mt = 0; mt < 4; mt++)
#pragma unroll
            for (int r = 0; r < 4; r++) {
                float e = exp2f((acc[mt][nt][r] - mx) * KSC);
                acc[mt][nt][r] = e;
                sum += e;
            }
        sum += __shfl_xor(sum, 16);
        sum += __shfl_xor(sum, 32);
        float inv = 1.0f / sum;
        // pack 4 consecutive keys -> ds_write_b64 into P[query][key]
#pragma unroll
        for (int mt = 0; mt < 4; mt++) {
            uint32_t u01 = pk2(acc[mt][nt][0] * inv, acc[mt][nt][1] * inv);
            uint32_t u23 = pk2(acc[mt][nt][2] * inv, acc[mt][nt][3] * inv);
            *(uint2*)(sP + (c15 + 16 * nt) * 72 + 4 * q + 16 * mt) =
                make_uint2(u01, u23);
        }
    }

    // PV: O^T[d][query] = sum_key V^T[d][key] * P[query][key]
    bf16x8 pf[4][2], vf[2][2];
#pragma unroll
    for (int nt = 0; nt < 4; nt++)
#pragma unroll
        for (int ks = 0; ks < 2; ks++)
            pf[nt][ks] = *(const bf16x8*)(sP + (c15 + 16 * nt) * 72 + q * 8 + 32 * ks);
#pragma unroll
    for (int mt = 0; mt < 2; mt++)
#pragma unroll
        for (int ks = 0; ks < 2; ks++)
            vf[mt][ks] = *(const bf16x8*)(sVT + (c15 + 16 * mt) * 72 + q * 8 + 32 * ks);

    f32x4 oacc[2][4];
#pragma unroll
    for (int mt = 0; mt < 2; mt++)
#pragma unroll
        for (int nt = 0; nt < 4; nt++)
            oacc[mt][nt] = (f32x4){0.f, 0.f, 0.f, 0.f};
#pragma unroll
    for (int ks = 0; ks < 2; ks++)
#pragma unroll
        for (int mt = 0; mt < 2; mt++)
#pragma unroll
            for (int nt = 0; nt < 4; nt++)
                oacc[mt][nt] = __builtin_amdgcn_mfma_f32_16x16x32_bf16(
                    vf[mt][ks], pf[nt][ks], oacc[mt][nt], 0, 0, 0);

    // store: lane's query col = c15+16nt (valid<49), rows d = 4q+r+16mt
#pragma unroll
    for (int nt = 0; nt < 4; nt++) {
        if (valid[nt]) {
            unsigned short* dst = outt + (size_t)p_t[nt] * CDIM + h * HD + 4 * q;
#pragma unroll
            for (int mt = 0; mt < 2; mt++) {
                uint32_t u01 = pk2(oacc[mt][nt][0], oacc[mt][nt][1]);
                uint32_t u23 = pk2(oacc[mt][nt][2], oacc[mt][nt][3]);
                *(uint2*)(dst + 16 * mt) = make_uint2(u01, u23);
            }
        }
    }
}

// ---------------------------------------------------------------------------
// Launch
// ---------------------------------------------------------------------------
extern "C" void kernel_launch(void* const* d_in, const int* in_sizes, int n_in,
                              void* d_out, int out_size, void* d_ws, size_t ws_size,
                              hipStream_t stream) {
    const float* x      = (const float*)d_in[0];
    const float* w_qkv  = (const float*)d_in[1];
    const float* btab   = (const float*)d_in[2];
    const float* w_proj = (const float*)d_in[3];
    const float* b_proj = (const float*)d_in[4];
    float* out = (float*)d_out;

    // workspace layout (bytes)
    char* ws = (char*)d_ws;
    const size_t off_xt   = 0;                         // 77,070,336 (reused as out_t)
    const size_t off_qkv  = 77070336;                  // 231,211,008
    const size_t off_wq   = off_qkv + 231211008;       // 884,736
    const size_t off_wp   = off_wq + 884736;           // 294,912
    const size_t off_bt   = off_wp + 294912;           // 196,608
    unsigned short* xt   = (unsigned short*)(ws + off_xt);
    unsigned short* qkvt = (unsigned short*)(ws + off_qkv);
    unsigned short* wqb  = (unsigned short*)(ws + off_wq);
    unsigned short* wpb  = (unsigned short*)(ws + off_wp);
    float*          bt   = (float*)(ws + off_bt);
    unsigned short* outt = xt;   // alias: xt dead after gemm_qkv

    cvt_f32_bf16<<<(C3 * CDIM / 4 + 255) / 256, 256, 0, stream>>>(w_qkv, wqb, C3 * CDIM / 4);
    cvt_f32_bf16<<<(CDIM * CDIM / 4 + 255) / 256, 256, 0, stream>>>(w_proj, wpb, CDIM * CDIM / 4);
    bias_pre<<<192, 256, 0, stream>>>(btab, bt);
    transpose_x<<<dim3(98, 12, 32), dim3(32, 8), 0, stream>>>(x, xt);
    gemm_qkv<<<dim3(9, 784), 256, 0, stream>>>(xt, wqb, qkvt);
    attn_mfma<<<dim3(NWIN, NHEAD), 64, 0, stream>>>(qkvt, bt, outt);
    gemm_proj<<<dim3(784, 3), 256, 0, stream>>>(wpb, outt, b_proj, out);
}

// Round 4
// 584.448 us; speedup vs baseline: 1.0416x; 1.0281x over previous
//
#include <hip/hip_runtime.h>
#include <hip/hip_bf16.h>
#include <cstdint>
#include <cstddef>

// Problem constants
#define NP     100352      // 32*56*56 total pixels
#define HW     3136        // 56*56
#define CDIM   384
#define C3     1152        // 3*384
#define NHEAD  12
#define HD     32          // head dim
#define NWIN   2048        // 32 * 8 * 8 windows

typedef __attribute__((ext_vector_type(8))) short bf16x8;
typedef __attribute__((ext_vector_type(4))) float f32x4;

static __device__ __forceinline__ float bf2f(unsigned short u) {
    union { float f; uint32_t i; } v; v.i = ((uint32_t)u) << 16; return v.f;
}
static __device__ __forceinline__ unsigned short f2bf(float f) {
    union { float f; uint32_t i; } v; v.f = f;
    uint32_t r = v.i + 0x7FFFu + ((v.i >> 16) & 1u);   // round-nearest-even
    return (unsigned short)(r >> 16);
}
// pack two f32 -> bf16 pair (round-half-up; lo half = a)
static __device__ __forceinline__ uint32_t pk2(float a, float b) {
    union { float f; uint32_t u; } x, y; x.f = a; y.f = b;
    return ((x.u + 0x8000u) >> 16) | ((y.u + 0x8000u) & 0xffff0000u);
}

// async global->LDS, 16B per lane; LDS dest = wave-uniform base + lane*16
static __device__ __forceinline__ void gld_lds16(const void* g, void* l) {
    __builtin_amdgcn_global_load_lds(
        (const __attribute__((address_space(1))) void*)g,
        (__attribute__((address_space(3))) void*)l, 16, 0, 0);
}

// ---------------------------------------------------------------------------
// Kernel 1: fp32 -> bf16 weight conversion (vectorized x4)
// ---------------------------------------------------------------------------
__global__ __launch_bounds__(256) void cvt_f32_bf16(
    const float* __restrict__ src, unsigned short* __restrict__ dst, int n4) {
    int i = blockIdx.x * blockDim.x + threadIdx.x;
    if (i < n4) {
        float4 v = ((const float4*)src)[i];
        ushort4 r;
        r.x = f2bf(v.x); r.y = f2bf(v.y); r.z = f2bf(v.z); r.w = f2bf(v.w);
        ((ushort4*)dst)[i] = r;
    }
}

// ---------------------------------------------------------------------------
// Kernel 1b: precompute bias_t[h][query][key] fp32 (64x64 padded, / scale,
// -1e30 on pads so softmax masking is free). 12*64*64 = 49152 elems.
// ---------------------------------------------------------------------------
__global__ __launch_bounds__(256) void bias_pre(
    const float* __restrict__ btab, float* __restrict__ bias_t) {
    int idx = blockIdx.x * 256 + threadIdx.x;
    int h = idx >> 12, query = (idx >> 6) & 63, key = idx & 63;
    float v = -1e30f;
    if (query < 49 && key < 49) {
        int ri = query / 7, rj = query % 7, mi = key / 7, mj = key % 7;
        v = btab[((ri - mi + 6) * 13 + (rj - mj + 6)) * NHEAD + h] * 5.656854249492381f;
    }
    bias_t[idx] = v;
}

// ---------------------------------------------------------------------------
// Kernel 2: transpose x (B, C, HW) fp32 -> xt (B*HW, C) bf16
// grid (98, 12, 32), block (32, 8)
// ---------------------------------------------------------------------------
__global__ __launch_bounds__(256) void transpose_x(
    const float* __restrict__ x, unsigned short* __restrict__ xt) {
    __shared__ float tile[32][33];
    int b   = blockIdx.z;
    int hw0 = blockIdx.x * 32;
    int c0  = blockIdx.y * 32;
    int tx = threadIdx.x, ty = threadIdx.y;
    const float* xp = x + (size_t)b * CDIM * HW;
#pragma unroll
    for (int i = 0; i < 4; i++) {
        int c = ty + i * 8;
        tile[c][tx] = xp[(size_t)(c0 + c) * HW + hw0 + tx];   // coalesced along hw
    }
    __syncthreads();
    unsigned short* xtp = xt + (size_t)b * HW * CDIM;
#pragma unroll
    for (int i = 0; i < 4; i++) {
        int r = ty + i * 8;                                   // local hw
        xtp[(size_t)(hw0 + r) * CDIM + c0 + tx] = f2bf(tile[tx][r]);  // coalesced along c
    }
}

// ---------------------------------------------------------------------------
// 8-phase MFMA GEMM core (T3+T4+T2+T5). K = 384 = 6 K-tiles of BK=64.
// 512 threads = 8 waves (WM x WN), per-wave 64x64 output (4x4 16x16 frags).
// Ring of 3 LDS K-tile buffers (A BM x 64 + B BN x 64 bf16 each = 48 KB).
// Staging runs 2 K-tiles ahead -> counted s_waitcnt vmcnt(9) (never 0 in
// steady state). Raw s_barrier (no compiler vmcnt(0) drain). LDS slot-XOR
// swizzle (slot ^= row&7) applied on the READ side; inverse XOR pre-applied
// to the per-lane GLOBAL source address (global_load_lds dest stays linear).
// s_setprio(1) around each 16-MFMA cluster. sched_barrier(0) after each
// hand-placed waitcnt pins the compiler against migrating memory ops.
// vmcnt ledger: issued at iter-t phaseA wait = 12 + 6t + 3; tile-t landed
// means first 6(t+1) retired -> allowed outstanding = exactly 9.
// ---------------------------------------------------------------------------
template<int BM, int BN, int WM, int WN>
static __device__ __forceinline__ void gemm8(
    const unsigned short* __restrict__ A, const unsigned short* __restrict__ Bt,
    int m0, int n0, unsigned short* lds, f32x4 acc[4][4]) {

    constexpr int NA   = BM / 64;          // A stage-calls per K-tile (per thread)
    constexpr int BUFE = (BM + BN) * 64;   // elems per ring buffer

    const int tid  = threadIdx.x;
    const int wv   = tid >> 6;
    const int lane = tid & 63;
    const int wc = wv & (WN - 1), wr = wv / WN;
    const int lrow = lane & 15, lq = lane >> 4;
    const int lr8  = lane >> 3;                 // row within 8-row chunk
    const int gsl  = ((lane & 7) ^ lr8) << 3;   // inverse-swizzled slot, elems

#pragma unroll
    for (int i = 0; i < 4; i++)
#pragma unroll
        for (int j = 0; j < 4; j++) acc[i][j] = (f32x4){0.f, 0.f, 0.f, 0.f};

    // stage call s of K-tile kt into ring buffer bufi.
    // One call = 1024B per wave (8 rows x 128B); chunk id = s*8 + wv.
    auto stage = [&](int s, int kt, int bufi) {
        if (s < NA) {
            int grow = m0 + s * 64 + wv * 8 + lr8;
            gld_lds16(A + (size_t)grow * 384 + kt * 64 + gsl,
                      lds + bufi * BUFE + (s * 8 + wv) * 512);
        } else {
            int sj = s - NA;
            int grow = n0 + sj * 64 + wv * 8 + lr8;
            gld_lds16(Bt + (size_t)grow * 384 + kt * 64 + gsl,
                      lds + bufi * BUFE + BM * 64 + (sj * 8 + wv) * 512);
        }
    };

    // prologue: stage K-tiles 0 and 1 (12 loads outstanding per thread)
#pragma unroll
    for (int s = 0; s < 6; s++) stage(s, 0, 0);
#pragma unroll
    for (int s = 0; s < 6; s++) stage(s, 1, 1);

#pragma unroll
    for (int t = 0; t < 6; t++) {
        const int bufi = t % 3, nbuf = (t + 2) % 3;
        const unsigned short* la = lds + bufi * BUFE;
        const unsigned short* lb = la + BM * 64;
        bf16x8 af[4][2], bfr[2][2];

        // ------------- phase A (C cols 0..31 of wave tile) -------------
        if (t < 4) { stage(0, t + 2, nbuf); stage(1, t + 2, nbuf); stage(2, t + 2, nbuf); }
        // counted wait: oldest-beyond-N loads (= K-tile t) have landed
        if (t < 4)       asm volatile("s_waitcnt vmcnt(9)" ::: "memory");
        else if (t == 4) asm volatile("s_waitcnt vmcnt(6)" ::: "memory");
        else             asm volatile("s_waitcnt vmcnt(0)" ::: "memory");
        __builtin_amdgcn_sched_barrier(0);
        __builtin_amdgcn_s_barrier();   // collective: tile t ready everywhere

#pragma unroll
        for (int mi = 0; mi < 4; mi++)
#pragma unroll
            for (int ks = 0; ks < 2; ks++)
                af[mi][ks] = *(const bf16x8*)(la + (wr * 64 + mi * 16 + lrow) * 64 +
                                              (((ks * 4 + lq) ^ (lrow & 7)) << 3));
#pragma unroll
        for (int ni = 0; ni < 2; ni++)
#pragma unroll
            for (int ks = 0; ks < 2; ks++)
                bfr[ni][ks] = *(const bf16x8*)(lb + (wc * 64 + ni * 16 + lrow) * 64 +
                                               (((ks * 4 + lq) ^ (lrow & 7)) << 3));
        __builtin_amdgcn_s_setprio(1);
#pragma unroll
        for (int mi = 0; mi < 4; mi++)
#pragma unroll
            for (int ni = 0; ni < 2; ni++)
#pragma unroll
                for (int ks = 0; ks < 2; ks++)
                    acc[mi][ni] = __builtin_amdgcn_mfma_f32_16x16x32_bf16(
                        af[mi][ks], bfr[ni][ks], acc[mi][ni], 0, 0, 0);
        __builtin_amdgcn_s_setprio(0);
        __builtin_amdgcn_s_barrier();

        // ------------- phase B (C cols 32..63 of wave tile) -------------
        if (t < 4) { stage(3, t + 2, nbuf); stage(4, t + 2, nbuf); stage(5, t + 2, nbuf); }
        __builtin_amdgcn_s_barrier();
#pragma unroll
        for (int ni = 0; ni < 2; ni++)
#pragma unroll
            for (int ks = 0; ks < 2; ks++)
                bfr[ni][ks] = *(const bf16x8*)(lb + (wc * 64 + (ni + 2) * 16 + lrow) * 64 +
                                               (((ks * 4 + lq) ^ (lrow & 7)) << 3));
        __builtin_amdgcn_s_setprio(1);
#pragma unroll
        for (int mi = 0; mi < 4; mi++)
#pragma unroll
            for (int ni = 0; ni < 2; ni++)
#pragma unroll
                for (int ks = 0; ks < 2; ks++)
                    acc[mi][ni + 2] = __builtin_amdgcn_mfma_f32_16x16x32_bf16(
                        af[mi][ks], bfr[ni][ks], acc[mi][ni + 2], 0, 0, 0);
        __builtin_amdgcn_s_setprio(0);
        __builtin_amdgcn_s_barrier();
    }
}

// GEMM 1: qkv_t[p][o] = sum_c xt[p][c] * w_qkv[o][c]; output bf16, ldc = 1152
// BM=256 (p), BN=128 (o): grid 392*9 = 3528 = 8*441 (bijective XCD chunking,
// the 9 n-tiles sharing one 192 KB A-panel adjacent on the same XCD L2).
__global__ __launch_bounds__(512) void gemm_qkv8(
    const unsigned short* __restrict__ A, const unsigned short* __restrict__ Bt,
    unsigned short* __restrict__ C) {
    __shared__ __align__(16) unsigned short lds[3 * (256 + 128) * 64];  // 144 KiB
    int lin = blockIdx.x;
    int xcd = lin & 7, pos = lin >> 3;
    int nid = xcd * 441 + pos;              // bijective: 3528 = 8*441
    int m0 = (nid / 9) * 256;
    int n0 = (nid % 9) * 128;
    f32x4 acc[4][4];
    gemm8<256, 128, 4, 2>(A, Bt, m0, n0, lds, acc);

    int lane = threadIdx.x & 63, wv = threadIdx.x >> 6;
    int wc = wv & 1, wr = wv >> 1;
    int lrow = lane & 15, lq = lane >> 4;
#pragma unroll
    for (int mi = 0; mi < 4; mi++)
#pragma unroll
        for (int ni = 0; ni < 4; ni++)
#pragma unroll
            for (int i = 0; i < 4; i++) {
                int row = m0 + wr * 64 + mi * 16 + lq * 4 + i;   // p
                int col = n0 + wc * 64 + ni * 16 + lrow;         // o
                C[(size_t)row * C3 + col] = f2bf(acc[mi][ni][i]);
            }
}

// GEMM 2: out[b][o][hw] = sum_c w_proj[o][c] * out_t[p][c] + b_proj[o]
// BM=128 (o), BN=256 (p): grid 3*392 = 1176 = 8*147; the 3 m-blocks sharing
// one 192 KB outt panel adjacent on the same XCD L2.
__global__ __launch_bounds__(512) void gemm_proj8(
    const unsigned short* __restrict__ A, const unsigned short* __restrict__ Bt,
    const float* __restrict__ bias, float* __restrict__ out) {
    __shared__ __align__(16) unsigned short lds[3 * (128 + 256) * 64];  // 144 KiB
    int lin = blockIdx.x;
    int xcd = lin & 7, pos = lin >> 3;
    int nid = xcd * 147 + pos;              // bijective: 1176 = 8*147
    int m0 = (nid % 3) * 128;
    int n0 = (nid / 3) * 256;
    f32x4 acc[4][4];
    gemm8<128, 256, 2, 4>(A, Bt, m0, n0, lds, acc);

    int lane = threadIdx.x & 63, wv = threadIdx.x >> 6;
    int wc = wv & 3, wr = wv >> 2;
    int lrow = lane & 15, lq = lane >> 4;
#pragma unroll
    for (int mi = 0; mi < 4; mi++)
#pragma unroll
        for (int ni = 0; ni < 4; ni++) {
            int pcol = n0 + wc * 64 + ni * 16 + lrow;            // global pixel p
            int b = pcol / HW, hw = pcol - b * HW;
#pragma unroll
            for (int i = 0; i < 4; i++) {
                int o = m0 + wr * 64 + mi * 16 + lq * 4 + i;
                out[(size_t)b * CDIM * HW + (size_t)o * HW + hw] = acc[mi][ni][i] + bias[o];
            }
        }
}

// ---------------------------------------------------------------------------
// Kernel 4: MFMA window attention. grid (2048, 12), block 64 (1 wave).
// Computes S^T = K.Q^T (A=K, B=Q frags read DIRECTLY from qkvt: natural
// layout), C-init = bias_t[h][query][key] (bias/scale, -1e30 pads -> free
// masking). Softmax over keys = per-lane 16-reg reduce + shfl_xor(16,32).
// P[query][key] -> LDS (rows padded to 72 elems, 16B-aligned b128 reads).
// O^T = V^T.P^T via MFMA; V^T built by b16 scatter at staging.
// ---------------------------------------------------------------------------
__global__ __launch_bounds__(64, 3) void attn_mfma(
    const unsigned short* __restrict__ qkv, const float* __restrict__ bias_t,
    unsigned short* __restrict__ outt) {
    int w = blockIdx.x, h = blockIdx.y;
    int lane = threadIdx.x;
    int q = lane >> 4, c15 = lane & 15;
    int b = w >> 6, wy = (w >> 3) & 7, wx = w & 7;
    int pbase = b * HW + wy * 7 * 56 + wx * 7;

    __shared__ __align__(16) unsigned short sVT[32 * 72];  // V^T[d][key]
    __shared__ __align__(16) unsigned short sP[64 * 72];   // P[query][key]

    // token -> pixel for tile index t (used by Q/K frags and O stores)
    int p_t[4]; int valid[4];
#pragma unroll
    for (int t = 0; t < 4; t++) {
        int tok = c15 + 16 * t;
        valid[t] = tok < 49;
        int tc = valid[t] ? tok : 48;             // clamp (finite garbage; bias masks)
        p_t[t] = pbase + (tc / 7) * 56 + (tc % 7);
    }

    // zero V^T (pad key columns must be finite)
    {
        uint4* z = (uint4*)sVT;                   // 32*72*2/16 = 288 chunks
#pragma unroll
        for (int i = 0; i < 5; i++) {
            int idx = lane + 64 * i;
            if (idx < 288) z[idx] = (uint4){0u, 0u, 0u, 0u};
        }
    }

    // K,Q fragments straight from global: frag[row=lane&15][k=q*8+j]
    bf16x8 kf[4], qf[4];
#pragma unroll
    for (int t = 0; t < 4; t++) {
        const unsigned short* base = qkv + (size_t)p_t[t] * C3 + h * HD + q * 8;
        qf[t] = *(const bf16x8*)(base);           // Q at o-offset 0
        kf[t] = *(const bf16x8*)(base + CDIM);    // K at o-offset 384
    }

    // stage V transposed: sVT[d][tok]
#pragma unroll
    for (int it = 0; it < 4; it++) {
        int c = lane + 64 * it;
        if (c < 196) {
            int tok = c >> 2, s = c & 3;
            int p = pbase + (tok / 7) * 56 + (tok % 7);
            uint4 v = *(const uint4*)(qkv + (size_t)p * C3 + 2 * CDIM + h * HD + s * 8);
            const unsigned short* vp = (const unsigned short*)&v;
#pragma unroll
            for (int i = 0; i < 8; i++)
                sVT[(8 * s + i) * 72 + tok] = vp[i];
        }
    }

    // S^T accumulators, C-init with bias_t[h][query][key] (float4-aligned)
    f32x4 acc[4][4];
    const float* bp = bias_t + (size_t)h * 64 * 64;
#pragma unroll
    for (int nt = 0; nt < 4; nt++) {
        const float* bq = bp + (c15 + 16 * nt) * 64 + 4 * q;
#pragma unroll
        for (int mt = 0; mt < 4; mt++)
            acc[mt][nt] = *(const f32x4*)(bq + 16 * mt);
    }

    // QK^T (K=32 in one MFMA step): acc[key-tile][query-tile]
#pragma unroll
    for (int mt = 0; mt < 4; mt++)
#pragma unroll
        for (int nt = 0; nt < 4; nt++)
            acc[mt][nt] = __builtin_amdgcn_mfma_f32_16x16x32_bf16(
                kf[mt], qf[nt], acc[mt][nt], 0, 0, 0);

    // softmax over keys, per query column; scale folded into exp2 constant:
    // S_ref = scale*(QK + bias/scale)  =>  e = exp2((acc - max) * scale*log2e)
    const float KSC = 0.25503472f;                // 2^-2.5 * log2(e)
#pragma unroll
    for (int nt = 0; nt < 4; nt++) {
        float mx = acc[0][nt][0];
#pragma unroll
        for (int mt = 0; mt < 4; mt++)
#pragma unroll
            for (int r = 0; r < 4; r++) mx = fmaxf(mx, acc[mt][nt][r]);
        mx = fmaxf(mx, __shfl_xor(mx, 16));
        mx = fmaxf(mx, __shfl_xor(mx, 32));
        float sum = 0.f;
#pragma unroll
        for (int mt = 0; mt < 4; mt++)
#pragma unroll
            for (int r = 0; r < 4; r++) {
                float e = exp2f((acc[mt][nt][r] - mx) * KSC);
                acc[mt][nt][r] = e;
                sum += e;
            }
        sum += __shfl_xor(sum, 16);
        sum += __shfl_xor(sum, 32);
        float inv = 1.0f / sum;
        // pack 4 consecutive keys -> ds_write_b64 into P[query][key]
#pragma unroll
        for (int mt = 0; mt < 4; mt++) {
            uint32_t u01 = pk2(acc[mt][nt][0] * inv, acc[mt][nt][1] * inv);
            uint32_t u23 = pk2(acc[mt][nt][2] * inv, acc[mt][nt][3] * inv);
            *(uint2*)(sP + (c15 + 16 * nt) * 72 + 4 * q + 16 * mt) =
                make_uint2(u01, u23);
        }
    }

    // PV: O^T[d][query] = sum_key V^T[d][key] * P[query][key]
    bf16x8 pf[4][2], vf[2][2];
#pragma unroll
    for (int nt = 0; nt < 4; nt++)
#pragma unroll
        for (int ks = 0; ks < 2; ks++)
            pf[nt][ks] = *(const bf16x8*)(sP + (c15 + 16 * nt) * 72 + q * 8 + 32 * ks);
#pragma unroll
    for (int mt = 0; mt < 2; mt++)
#pragma unroll
        for (int ks = 0; ks < 2; ks++)
            vf[mt][ks] = *(const bf16x8*)(sVT + (c15 + 16 * mt) * 72 + q * 8 + 32 * ks);

    f32x4 oacc[2][4];
#pragma unroll
    for (int mt = 0; mt < 2; mt++)
#pragma unroll
        for (int nt = 0; nt < 4; nt++)
            oacc[mt][nt] = (f32x4){0.f, 0.f, 0.f, 0.f};
#pragma unroll
    for (int ks = 0; ks < 2; ks++)
#pragma unroll
        for (int mt = 0; mt < 2; mt++)
#pragma unroll
            for (int nt = 0; nt < 4; nt++)
                oacc[mt][nt] = __builtin_amdgcn_mfma_f32_16x16x32_bf16(
                    vf[mt][ks], pf[nt][ks], oacc[mt][nt], 0, 0, 0);

    // store: lane's query col = c15+16nt (valid<49), rows d = 4q+r+16mt
#pragma unroll
    for (int nt = 0; nt < 4; nt++) {
        if (valid[nt]) {
            unsigned short* dst = outt + (size_t)p_t[nt] * CDIM + h * HD + 4 * q;
#pragma unroll
            for (int mt = 0; mt < 2; mt++) {
                uint32_t u01 = pk2(oacc[mt][nt][0], oacc[mt][nt][1]);
                uint32_t u23 = pk2(oacc[mt][nt][2], oacc[mt][nt][3]);
                *(uint2*)(dst + 16 * mt) = make_uint2(u01, u23);
            }
        }
    }
}

// ---------------------------------------------------------------------------
// Launch
// ---------------------------------------------------------------------------
extern "C" void kernel_launch(void* const* d_in, const int* in_sizes, int n_in,
                              void* d_out, int out_size, void* d_ws, size_t ws_size,
                              hipStream_t stream) {
    const float* x      = (const float*)d_in[0];
    const float* w_qkv  = (const float*)d_in[1];
    const float* btab   = (const float*)d_in[2];
    const float* w_proj = (const float*)d_in[3];
    const float* b_proj = (const float*)d_in[4];
    float* out = (float*)d_out;

    // workspace layout (bytes)
    char* ws = (char*)d_ws;
    const size_t off_xt   = 0;                         // 77,070,336 (reused as out_t)
    const size_t off_qkv  = 77070336;                  // 231,211,008
    const size_t off_wq   = off_qkv + 231211008;       // 884,736
    const size_t off_wp   = off_wq + 884736;           // 294,912
    const size_t off_bt   = off_wp + 294912;           // 196,608
    unsigned short* xt   = (unsigned short*)(ws + off_xt);
    unsigned short* qkvt = (unsigned short*)(ws + off_qkv);
    unsigned short* wqb  = (unsigned short*)(ws + off_wq);
    unsigned short* wpb  = (unsigned short*)(ws + off_wp);
    float*          bt   = (float*)(ws + off_bt);
    unsigned short* outt = xt;   // alias: xt dead after gemm_qkv

    cvt_f32_bf16<<<(C3 * CDIM / 4 + 255) / 256, 256, 0, stream>>>(w_qkv, wqb, C3 * CDIM / 4);
    cvt_f32_bf16<<<(CDIM * CDIM / 4 + 255) / 256, 256, 0, stream>>>(w_proj, wpb, CDIM * CDIM / 4);
    bias_pre<<<192, 256, 0, stream>>>(btab, bt);
    transpose_x<<<dim3(98, 12, 32), dim3(32, 8), 0, stream>>>(x, xt);
    gemm_qkv8<<<3528, 512, 0, stream>>>(xt, wqb, qkvt);
    attn_mfma<<<dim3(NWIN, NHEAD), 64, 0, stream>>>(qkvt, bt, outt);
    gemm_proj8<<<1176, 512, 0, stream>>>(wpb, outt, b_proj, out);
}